// Round 2
// baseline (233.985 us; speedup 1.0000x reference)
//
#include <hip/hip_runtime.h>

// YOLO loss: preds/targets (N,7,7,30) fp32 -> scalar.
// Memory-bound streaming reduction: 192.7 MB read, roofline ~30 us @ 6.3 TB/s.
//
// R3: drop global_load_lds entirely. R1 (gload_lds, 8 waves/CU, barrier-drain)
// and R2 (gload_lds, 5 persistent waves/CU, counted vmcnt, zero drains) BOTH
// landed at ~70 us / 2.7 TB/s -- structure-invariant, so the direct-to-LDS
// path itself caps streaming throughput (requests not truly concurrent).
// Proven 5-6.3 TB/s streamers (m13 copy, m219 LayerNorm @82% BW) use plain
// global_load_dwordx4 + high occupancy. So: reg-staged coalesced loads +
// ds_write transpose + 16-20 waves/CU of TLP.
//   - 256 thr/block, 128 cells/block -> LDS 30.7 KiB -> 4-5 blocks/CU.
//   - 8 independent dwordx4 loads/thread issued back-to-back, then ds_write.
//   - __syncthreads drain is covered by the other co-resident blocks (m114).
//   - threads 0..127 compute one cell each; compute is ~7% busy, wasting the
//     upper wave-pair in the compute phase is free.

#define SGRID 7
#define DDIM 30
#define NCLS 20
#define LAMBDA_NOOBJ 0.5f
#define IOU_EPS 1e-10f

#define CELLS 128
#define THREADS 256
#define NF4P (CELLS * DDIM / 4)                 // 960 float4 per tensor chunk
#define NF4 (2 * NF4P)                          // 1920 float4 per chunk
#define NPASS ((NF4 + THREADS - 1) / THREADS)   // 8 (pass 7 is half-active)

__device__ __forceinline__ float cell_loss(const float* pv, const float* tv) {
    float loss = 0.0f;

    // IoU per box (center format).
    float iou0, iou1;
#pragma unroll
    for (int b = 0; b < 2; ++b) {
        const float x1 = pv[b * 5 + 0], y1 = pv[b * 5 + 1];
        const float w1 = pv[b * 5 + 2], h1 = pv[b * 5 + 3];
        const float x2 = tv[b * 5 + 0], y2 = tv[b * 5 + 1];
        const float w2 = tv[b * 5 + 2], h2 = tv[b * 5 + 3];
        float iw = fminf(x1 + 0.5f * w1, x2 + 0.5f * w2) -
                   fmaxf(x1 - 0.5f * w1, x2 - 0.5f * w2);
        iw = fmaxf(iw, 0.0f);
        float ih = fminf(y1 + 0.5f * h1, y2 + 0.5f * h2) -
                   fmaxf(y1 - 0.5f * h1, y2 - 0.5f * h2);
        ih = fmaxf(ih, 0.0f);
        const float inter = iw * ih;
        const float uni = w1 * h1 + w2 * h2 - inter;
        const float iou = inter / (uni + IOU_EPS);
        if (b == 0) iou0 = iou; else iou1 = iou;
    }

    // argmax ties -> first index (box 0).
    const bool sel1 = iou1 > iou0;

    // coord loss (selected box x,y), gated by has_obj = targets[...,4] > 0.
    {
        const float px = sel1 ? pv[5] : pv[0];
        const float py = sel1 ? pv[6] : pv[1];
        const float tx = sel1 ? tv[5] : tv[0];
        const float ty = sel1 ? tv[6] : tv[1];
        const float dx = px - tx, dy = py - ty;
        if (tv[4] > 0.0f) loss += dx * dx + dy * dy;
    }

    // class SSE + running argmax of target class (ties -> first);
    // track pc_gt by value to avoid dynamic register indexing.
    float gt_val = tv[10];
    float pc_gt = pv[10];
#pragma unroll
    for (int j = 0; j < NCLS; ++j) {
        const float pc = pv[10 + j], tc = tv[10 + j];
        const float d = pc - tc;
        loss += d * d;
        const bool gm = tc > gt_val;
        gt_val = gm ? tc : gt_val;
        pc_gt = gm ? pc : pc_gt;
    }

    // conf loss: w_b * (iou_b * pc_gt - iou_b)^2 = w_b * iou_b^2 * (pc_gt-1)^2
    const float c = pc_gt - 1.0f;
    const float d0 = iou0 * c, d1 = iou1 * c;
    const float w0 = sel1 ? LAMBDA_NOOBJ : 1.0f;
    const float w1 = sel1 ? 1.0f : LAMBDA_NOOBJ;
    loss += w0 * d0 * d0 + w1 * d1 * d1;
    return loss;
}

__global__ __launch_bounds__(THREADS, 4) void yolo_loss_main(
    const float* __restrict__ preds, const float* __restrict__ targets,
    float* __restrict__ partials, int n_cells) {
    // 30720 B: preds chunk [0 .. NF4P*4) then targets chunk.
    __shared__ __align__(16) float sb[NF4 * 4];
    __shared__ float red[THREADS / 64];

    const int tid = threadIdx.x;
    const int cell0 = blockIdx.x * CELLS;
    float loss = 0.0f;

    if (cell0 + CELLS <= n_cells) {
        // ---- Stage: 8 independent coalesced dwordx4 loads per thread, all
        // issued before any ds_write (max memory-level parallelism), then
        // the LDS transpose writes.
        const long long base_f = (long long)cell0 * DDIM;
        const float4* gp = (const float4*)(preds + base_f);
        const float4* gt = (const float4*)(targets + base_f);
        float4 v[NPASS];
#pragma unroll
        for (int k = 0; k < NPASS; ++k) {
            const int i = tid + k * THREADS;
            if (i < NF4) {
                // Per-lane source select; only pass 3 actually mixes tensors.
                v[k] = (i < NF4P) ? gp[i] : gt[i - NF4P];
            }
        }
#pragma unroll
        for (int k = 0; k < NPASS; ++k) {
            const int i = tid + k * THREADS;
            if (i < NF4) *(float4*)(sb + i * 4) = v[k];
        }
        __syncthreads();  // drain covered by 4-5 co-resident blocks/CU

        // ---- Compute: one cell per thread for the lower 128 threads.
        if (tid < CELLS) {
            float pv[DDIM], tv[DDIM];
            const float2* p2 = (const float2*)(sb + tid * DDIM);            // 8B-aligned
            const float2* t2 = (const float2*)(sb + NF4P * 4 + tid * DDIM);
#pragma unroll
            for (int i = 0; i < DDIM / 2; ++i) {
                ((float2*)pv)[i] = p2[i];
                ((float2*)tv)[i] = t2[i];
            }
            loss = cell_loss(pv, tv);
        }
    } else {
        // ---- Ragged tail block (not hit at the bench shape): direct loads.
        const int cell = cell0 + tid;
        if (cell < n_cells) {
            const long long cb = (long long)cell * DDIM;
            float pv[DDIM], tv[DDIM];
            const float2* p2 = (const float2*)(preds + cb);  // 120B stride -> 8B-aligned
            const float2* t2 = (const float2*)(targets + cb);
#pragma unroll
            for (int i = 0; i < DDIM / 2; ++i) {
                ((float2*)pv)[i] = p2[i];
                ((float2*)tv)[i] = t2[i];
            }
            loss = cell_loss(pv, tv);
        }
    }

    // ---- Block reduction: wave shuffle tree, then cross-wave via LDS.
#pragma unroll
    for (int off = 32; off > 0; off >>= 1) loss += __shfl_down(loss, off, 64);
    if ((tid & 63) == 0) red[tid >> 6] = loss;
    __syncthreads();
    if (tid == 0) {
        float s = 0.0f;
#pragma unroll
        for (int w = 0; w < THREADS / 64; ++w) s += red[w];
        partials[blockIdx.x] = s;
    }
}

#define RTHREADS 1024
__global__ __launch_bounds__(RTHREADS) void yolo_loss_reduce(
    const float* __restrict__ partials, int n, float inv_n,
    float* __restrict__ out) {
    __shared__ float red[RTHREADS / 64];
    float v = 0.0f;
    for (int i = threadIdx.x; i < n; i += RTHREADS) v += partials[i];
#pragma unroll
    for (int off = 32; off > 0; off >>= 1) v += __shfl_down(v, off, 64);
    if ((threadIdx.x & 63) == 0) red[threadIdx.x >> 6] = v;
    __syncthreads();
    if (threadIdx.x == 0) {
        float s = 0.0f;
#pragma unroll
        for (int w = 0; w < RTHREADS / 64; ++w) s += red[w];
        out[0] = s * inv_n;
    }
}

extern "C" void kernel_launch(void* const* d_in, const int* in_sizes, int n_in,
                              void* d_out, int out_size, void* d_ws, size_t ws_size,
                              hipStream_t stream) {
    const float* preds = (const float*)d_in[0];
    const float* targets = (const float*)d_in[1];
    float* out = (float*)d_out;

    const int total = in_sizes[0];                        // N*S*S*D elements
    const int n_cells = total / DDIM;                     // N*S*S
    const int N = total / (SGRID * SGRID * DDIM);         // 16384
    const int nblocks = (n_cells + CELLS - 1) / CELLS;    // 6272 at bench shape

    float* partials = (float*)d_ws;  // nblocks floats; fully written before read

    yolo_loss_main<<<nblocks, THREADS, 0, stream>>>(preds, targets, partials, n_cells);
    yolo_loss_reduce<<<1, RTHREADS, 0, stream>>>(partials, nblocks, 1.0f / (float)N, out);
}

// Round 3
// 204.919 us; speedup vs baseline: 1.1418x; 1.1418x over previous
//
#include <hip/hip_runtime.h>

// YOLO loss: preds/targets (N,7,7,30) fp32 -> scalar.
// Memory-bound streaming reduction: 192.7 MB read, roofline ~30 us @ 6.3 TB/s.
//
// R4: R3's reg-staged + LDS-transpose + high-occupancy structure was right
// (48% occ, 3.8 TB/s total EA traffic), but the float4 v[8] staging array
// spilled to scratch (VGPR 88->44, WRITE_SIZE 0.1->188 MB = input-sized spill
// writebacks) -- half the traffic was garbage. Fix: stage in batches of 4
// float4 (16 VGPRs, static indices, fully unrolled: load 4 -> ds_write 4),
// so max live staging state is 64 B/thread and spilling is impossible.
//   - 256 thr/block, 128 cells/block -> LDS 30.7 KiB -> 4-5 blocks/CU,
//     16-20 waves/CU; 4 outstanding 1 KB wave-loads x 16+ waves = 64+ KB/CU
//     in flight >> Little's-law requirement.
//   - __syncthreads drain covered by co-resident blocks (m114 overlap).
//   - threads 0..127 compute one cell each from LDS.

#define SGRID 7
#define DDIM 30
#define NCLS 20
#define LAMBDA_NOOBJ 0.5f
#define IOU_EPS 1e-10f

#define CELLS 128
#define THREADS 256
#define NF4P (CELLS * DDIM / 4)   // 960 float4 per tensor chunk
#define NF4 (2 * NF4P)            // 1920 float4 per chunk (preds ++ targets)
// 1920 / 256 = 7.5 passes: 7 full + 1 half (tid < 128).

__device__ __forceinline__ float cell_loss(const float* pv, const float* tv) {
    float loss = 0.0f;

    // IoU per box (center format).
    float iou0, iou1;
#pragma unroll
    for (int b = 0; b < 2; ++b) {
        const float x1 = pv[b * 5 + 0], y1 = pv[b * 5 + 1];
        const float w1 = pv[b * 5 + 2], h1 = pv[b * 5 + 3];
        const float x2 = tv[b * 5 + 0], y2 = tv[b * 5 + 1];
        const float w2 = tv[b * 5 + 2], h2 = tv[b * 5 + 3];
        float iw = fminf(x1 + 0.5f * w1, x2 + 0.5f * w2) -
                   fmaxf(x1 - 0.5f * w1, x2 - 0.5f * w2);
        iw = fmaxf(iw, 0.0f);
        float ih = fminf(y1 + 0.5f * h1, y2 + 0.5f * h2) -
                   fmaxf(y1 - 0.5f * h1, y2 - 0.5f * h2);
        ih = fmaxf(ih, 0.0f);
        const float inter = iw * ih;
        const float uni = w1 * h1 + w2 * h2 - inter;
        const float iou = inter / (uni + IOU_EPS);
        if (b == 0) iou0 = iou; else iou1 = iou;
    }

    // argmax ties -> first index (box 0).
    const bool sel1 = iou1 > iou0;

    // coord loss (selected box x,y), gated by has_obj = targets[...,4] > 0.
    {
        const float px = sel1 ? pv[5] : pv[0];
        const float py = sel1 ? pv[6] : pv[1];
        const float tx = sel1 ? tv[5] : tv[0];
        const float ty = sel1 ? tv[6] : tv[1];
        const float dx = px - tx, dy = py - ty;
        if (tv[4] > 0.0f) loss += dx * dx + dy * dy;
    }

    // class SSE + running argmax of target class (ties -> first);
    // track pc_gt by value to avoid dynamic register indexing.
    float gt_val = tv[10];
    float pc_gt = pv[10];
#pragma unroll
    for (int j = 0; j < NCLS; ++j) {
        const float pc = pv[10 + j], tc = tv[10 + j];
        const float d = pc - tc;
        loss += d * d;
        const bool gm = tc > gt_val;
        gt_val = gm ? tc : gt_val;
        pc_gt = gm ? pc : pc_gt;
    }

    // conf loss: w_b * (iou_b * pc_gt - iou_b)^2 = w_b * iou_b^2 * (pc_gt-1)^2
    const float c = pc_gt - 1.0f;
    const float d0 = iou0 * c, d1 = iou1 * c;
    const float w0 = sel1 ? LAMBDA_NOOBJ : 1.0f;
    const float w1 = sel1 ? 1.0f : LAMBDA_NOOBJ;
    loss += w0 * d0 * d0 + w1 * d1 * d1;
    return loss;
}

__global__ __launch_bounds__(THREADS, 4) void yolo_loss_main(
    const float* __restrict__ preds, const float* __restrict__ targets,
    float* __restrict__ partials, int n_cells) {
    // 30720 B: preds chunk [0 .. NF4P*4) then targets chunk.
    __shared__ __align__(16) float sb[NF4 * 4];
    __shared__ float red[THREADS / 64];

    const int tid = threadIdx.x;
    const int cell0 = blockIdx.x * CELLS;
    float loss = 0.0f;

    if (cell0 + CELLS <= n_cells) {
        const long long base_f = (long long)cell0 * DDIM;
        const float4* gp = (const float4*)(preds + base_f);
        const float4* gt = (const float4*)(targets + base_f);

        // ---- Stage round A: passes 0..3 (4 float4 = 16 VGPRs, no spill).
        {
            float4 v0, v1, v2, v3;
            const int i0 = tid + 0 * THREADS;
            const int i1 = tid + 1 * THREADS;
            const int i2 = tid + 2 * THREADS;
            const int i3 = tid + 3 * THREADS;  // crosses 960: per-lane select
            v0 = gp[i0];
            v1 = gp[i1];
            v2 = gp[i2];
            v3 = (i3 < NF4P) ? gp[i3] : gt[i3 - NF4P];
            *(float4*)(sb + i0 * 4) = v0;
            *(float4*)(sb + i1 * 4) = v1;
            *(float4*)(sb + i2 * 4) = v2;
            *(float4*)(sb + i3 * 4) = v3;
        }
        // ---- Stage round B: passes 4..6 + half pass 7 (tid < 128).
        {
            float4 v0, v1, v2, v3;
            const int i0 = tid + 4 * THREADS;
            const int i1 = tid + 5 * THREADS;
            const int i2 = tid + 6 * THREADS;
            const int i3 = tid + 7 * THREADS;  // valid iff tid < 128
            v0 = gt[i0 - NF4P];
            v1 = gt[i1 - NF4P];
            v2 = gt[i2 - NF4P];
            if (tid < 128) v3 = gt[i3 - NF4P];
            *(float4*)(sb + i0 * 4) = v0;
            *(float4*)(sb + i1 * 4) = v1;
            *(float4*)(sb + i2 * 4) = v2;
            if (tid < 128) *(float4*)(sb + i3 * 4) = v3;
        }
        __syncthreads();  // drain covered by 4-5 co-resident blocks/CU

        // ---- Compute: one cell per thread for the lower 128 threads.
        if (tid < CELLS) {
            float pv[DDIM], tv[DDIM];
            const float2* p2 = (const float2*)(sb + tid * DDIM);            // 8B-aligned
            const float2* t2 = (const float2*)(sb + NF4P * 4 + tid * DDIM);
#pragma unroll
            for (int i = 0; i < DDIM / 2; ++i) {
                ((float2*)pv)[i] = p2[i];
                ((float2*)tv)[i] = t2[i];
            }
            loss = cell_loss(pv, tv);
        }
    } else {
        // ---- Ragged tail block (not hit at the bench shape): direct loads.
        const int cell = cell0 + tid;
        if (cell < n_cells) {
            const long long cb = (long long)cell * DDIM;
            float pv[DDIM], tv[DDIM];
            const float2* p2 = (const float2*)(preds + cb);  // 120B stride -> 8B-aligned
            const float2* t2 = (const float2*)(targets + cb);
#pragma unroll
            for (int i = 0; i < DDIM / 2; ++i) {
                ((float2*)pv)[i] = p2[i];
                ((float2*)tv)[i] = t2[i];
            }
            loss = cell_loss(pv, tv);
        }
    }

    // ---- Block reduction: wave shuffle tree, then cross-wave via LDS.
#pragma unroll
    for (int off = 32; off > 0; off >>= 1) loss += __shfl_down(loss, off, 64);
    if ((tid & 63) == 0) red[tid >> 6] = loss;
    __syncthreads();
    if (tid == 0) {
        float s = 0.0f;
#pragma unroll
        for (int w = 0; w < THREADS / 64; ++w) s += red[w];
        partials[blockIdx.x] = s;
    }
}

#define RTHREADS 1024
__global__ __launch_bounds__(RTHREADS) void yolo_loss_reduce(
    const float* __restrict__ partials, int n, float inv_n,
    float* __restrict__ out) {
    __shared__ float red[RTHREADS / 64];
    float v = 0.0f;
    for (int i = threadIdx.x; i < n; i += RTHREADS) v += partials[i];
#pragma unroll
    for (int off = 32; off > 0; off >>= 1) v += __shfl_down(v, off, 64);
    if ((threadIdx.x & 63) == 0) red[threadIdx.x >> 6] = v;
    __syncthreads();
    if (threadIdx.x == 0) {
        float s = 0.0f;
#pragma unroll
        for (int w = 0; w < RTHREADS / 64; ++w) s += red[w];
        out[0] = s * inv_n;
    }
}

extern "C" void kernel_launch(void* const* d_in, const int* in_sizes, int n_in,
                              void* d_out, int out_size, void* d_ws, size_t ws_size,
                              hipStream_t stream) {
    const float* preds = (const float*)d_in[0];
    const float* targets = (const float*)d_in[1];
    float* out = (float*)d_out;

    const int total = in_sizes[0];                        // N*S*S*D elements
    const int n_cells = total / DDIM;                     // N*S*S
    const int N = total / (SGRID * SGRID * DDIM);         // 16384
    const int nblocks = (n_cells + CELLS - 1) / CELLS;    // 6272 at bench shape

    float* partials = (float*)d_ws;  // nblocks floats; fully written before read

    yolo_loss_main<<<nblocks, THREADS, 0, stream>>>(preds, targets, partials, n_cells);
    yolo_loss_reduce<<<1, RTHREADS, 0, stream>>>(partials, nblocks, 1.0f / (float)N, out);
}

// Round 5
// 204.661 us; speedup vs baseline: 1.1433x; 1.0013x over previous
//
#include <hip/hip_runtime.h>

// YOLO loss: preds/targets (N,7,7,30) fp32 -> scalar.
// Memory-bound streaming reduction: 192.7 MB logical read.
//
// R6 == R5 rerun (R5 died to an infra/container failure, no counters; source
// re-audited -- nothing can hang: finite grid, bounded indices, no barriers).
// The definitive streaming test: R0..R4 -- four different schedules -- ALL
// land at 69-71 us (2.75 TB/s read-only, ~87% of the m13 copy's
// per-direction read rate). Every one had either global_load_lds (R1/R2) or
// __syncthreads + 6272-block churn (R0/R3/R4). This version is the
// BabelStream-dot analog: persistent single-wave blocks, plain coalesced
// dwordx4 loads, per-wave-private LDS slice (15 KiB -> 10 waves/CU), ZERO
// barriers, zero block churn, named-scalar staging regs (R3's array spilled).
// Same-wave ds_write -> ds_read needs no sync (in-order LDS pipe per wave);
// compiler inserts the vmcnt/lgkmcnt waits.
// If this also lands at ~70 us, the read path is hardware-capped -> roofline.

#define SGRID 7
#define DDIM 30
#define NCLS 20
#define LAMBDA_NOOBJ 0.5f
#define IOU_EPS 1e-10f

#define CHUNK 64                  // cells per chunk = one wave's tile
#define THREADS 64                // one wave per block
#define NF4P (CHUNK * DDIM / 4)   // 480 float4 per tensor per chunk
#define NF4 (2 * NF4P)            // 960 float4 per chunk; 15 per lane
#define GRIDB 2560                // 10 blocks/CU * 256 CU (LDS 15.36 KB -> 10/CU)

__device__ __forceinline__ float cell_loss(const float* pv, const float* tv) {
    float loss = 0.0f;

    // IoU per box (center format).
    float iou0, iou1;
#pragma unroll
    for (int b = 0; b < 2; ++b) {
        const float x1 = pv[b * 5 + 0], y1 = pv[b * 5 + 1];
        const float w1 = pv[b * 5 + 2], h1 = pv[b * 5 + 3];
        const float x2 = tv[b * 5 + 0], y2 = tv[b * 5 + 1];
        const float w2 = tv[b * 5 + 2], h2 = tv[b * 5 + 3];
        float iw = fminf(x1 + 0.5f * w1, x2 + 0.5f * w2) -
                   fmaxf(x1 - 0.5f * w1, x2 - 0.5f * w2);
        iw = fmaxf(iw, 0.0f);
        float ih = fminf(y1 + 0.5f * h1, y2 + 0.5f * h2) -
                   fmaxf(y1 - 0.5f * h1, y2 - 0.5f * h2);
        ih = fmaxf(ih, 0.0f);
        const float inter = iw * ih;
        const float uni = w1 * h1 + w2 * h2 - inter;
        const float iou = inter / (uni + IOU_EPS);
        if (b == 0) iou0 = iou; else iou1 = iou;
    }

    // argmax ties -> first index (box 0).
    const bool sel1 = iou1 > iou0;

    // coord loss (selected box x,y), gated by has_obj = targets[...,4] > 0.
    {
        const float px = sel1 ? pv[5] : pv[0];
        const float py = sel1 ? pv[6] : pv[1];
        const float tx = sel1 ? tv[5] : tv[0];
        const float ty = sel1 ? tv[6] : tv[1];
        const float dx = px - tx, dy = py - ty;
        if (tv[4] > 0.0f) loss += dx * dx + dy * dy;
    }

    // class SSE + running argmax of target class (ties -> first);
    // track pc_gt by value to avoid dynamic register indexing.
    float gt_val = tv[10];
    float pc_gt = pv[10];
#pragma unroll
    for (int j = 0; j < NCLS; ++j) {
        const float pc = pv[10 + j], tc = tv[10 + j];
        const float d = pc - tc;
        loss += d * d;
        const bool gm = tc > gt_val;
        gt_val = gm ? tc : gt_val;
        pc_gt = gm ? pc : pc_gt;
    }

    // conf loss: w_b * (iou_b * pc_gt - iou_b)^2 = w_b * iou_b^2 * (pc_gt-1)^2
    const float c = pc_gt - 1.0f;
    const float d0 = iou0 * c, d1 = iou1 * c;
    const float w0 = sel1 ? LAMBDA_NOOBJ : 1.0f;
    const float w1 = sel1 ? 1.0f : LAMBDA_NOOBJ;
    loss += w0 * d0 * d0 + w1 * d1 * d1;
    return loss;
}

__global__ __launch_bounds__(THREADS) void yolo_loss_main(
    const float* __restrict__ preds, const float* __restrict__ targets,
    float* __restrict__ partials, int n_cells) {
    // Wave-private slice: preds floats [0..1920), targets [1920..3840).
    __shared__ __align__(16) float sb[NF4 * 4];  // 15360 B -> 10 blocks/CU

    const int tid = threadIdx.x;  // lane
    const int nfull = n_cells / CHUNK;
    float loss = 0.0f;

    for (int c = blockIdx.x; c < nfull; c += GRIDB) {
        const long long base = (long long)c * (CHUNK * DDIM);
        const float4* gp = (const float4*)(preds + base);
        const float4* gt = (const float4*)(targets + base);

        // Stage 15 float4/lane in 3 batches of 5 named scalars (20 VGPRs
        // live max -> no spill possible). Per-lane src select only at k=7.
        {   // k = 0..4 : all preds
            float4 v0 = gp[tid], v1 = gp[tid + 64], v2 = gp[tid + 128],
                   v3 = gp[tid + 192], v4 = gp[tid + 256];
            *(float4*)(sb + (tid) * 4) = v0;
            *(float4*)(sb + (tid + 64) * 4) = v1;
            *(float4*)(sb + (tid + 128) * 4) = v2;
            *(float4*)(sb + (tid + 192) * 4) = v3;
            *(float4*)(sb + (tid + 256) * 4) = v4;
        }
        {   // k = 5..9 : k=7 straddles the preds/targets boundary (i=480)
            const int i7 = tid + 448;
            float4 v0 = gp[tid + 320], v1 = gp[tid + 384],
                   v2 = (i7 < NF4P) ? gp[i7] : gt[i7 - NF4P],
                   v3 = gt[tid + 32], v4 = gt[tid + 96];
            *(float4*)(sb + (tid + 320) * 4) = v0;
            *(float4*)(sb + (tid + 384) * 4) = v1;
            *(float4*)(sb + (tid + 448) * 4) = v2;
            *(float4*)(sb + (tid + 512) * 4) = v3;
            *(float4*)(sb + (tid + 576) * 4) = v4;
        }
        {   // k = 10..14 : all targets
            float4 v0 = gt[tid + 160], v1 = gt[tid + 224], v2 = gt[tid + 288],
                   v3 = gt[tid + 352], v4 = gt[tid + 416];
            *(float4*)(sb + (tid + 640) * 4) = v0;
            *(float4*)(sb + (tid + 704) * 4) = v1;
            *(float4*)(sb + (tid + 768) * 4) = v2;
            *(float4*)(sb + (tid + 832) * 4) = v3;
            *(float4*)(sb + (tid + 896) * 4) = v4;
        }

        // Same wave reads back its own writes: lgkmcnt waits are enough
        // (LDS ops from one wave complete in order) -- no barrier.
        float pv[DDIM], tv[DDIM];
        {
            const float2* p2 = (const float2*)(sb + tid * DDIM);            // 8B-aligned
            const float2* t2 = (const float2*)(sb + NF4P * 4 + tid * DDIM);
#pragma unroll
            for (int i = 0; i < DDIM / 2; ++i) {
                ((float2*)pv)[i] = p2[i];
                ((float2*)tv)[i] = t2[i];
            }
        }
        loss += cell_loss(pv, tv);
        // Next iteration's ds_writes issue after these ds_reads (in-order
        // per-wave LDS pipe) -> no WAR hazard on the slice.
    }

    // Ragged tail (< CHUNK cells; zero at bench shape): block 0, direct loads.
    const int tail0 = nfull * CHUNK;
    if (blockIdx.x == 0 && tail0 + tid < n_cells) {
        const long long cb = (long long)(tail0 + tid) * DDIM;
        float pv[DDIM], tv[DDIM];
        const float2* p2 = (const float2*)(preds + cb);  // 120B stride -> 8B-aligned
        const float2* t2 = (const float2*)(targets + cb);
#pragma unroll
        for (int i = 0; i < DDIM / 2; ++i) {
            ((float2*)pv)[i] = p2[i];
            ((float2*)tv)[i] = t2[i];
        }
        loss += cell_loss(pv, tv);
    }

    // Wave-level reduction (block == one wave), one store per block.
#pragma unroll
    for (int off = 32; off > 0; off >>= 1) loss += __shfl_down(loss, off, 64);
    if (tid == 0) partials[blockIdx.x] = loss;
}

#define RTHREADS 1024
__global__ __launch_bounds__(RTHREADS) void yolo_loss_reduce(
    const float* __restrict__ partials, int n, float inv_n,
    float* __restrict__ out) {
    __shared__ float red[RTHREADS / 64];
    float v = 0.0f;
    for (int i = threadIdx.x; i < n; i += RTHREADS) v += partials[i];
#pragma unroll
    for (int off = 32; off > 0; off >>= 1) v += __shfl_down(v, off, 64);
    if ((threadIdx.x & 63) == 0) red[threadIdx.x >> 6] = v;
    __syncthreads();
    if (threadIdx.x == 0) {
        float s = 0.0f;
#pragma unroll
        for (int w = 0; w < RTHREADS / 64; ++w) s += red[w];
        out[0] = s * inv_n;
    }
}

extern "C" void kernel_launch(void* const* d_in, const int* in_sizes, int n_in,
                              void* d_out, int out_size, void* d_ws, size_t ws_size,
                              hipStream_t stream) {
    const float* preds = (const float*)d_in[0];
    const float* targets = (const float*)d_in[1];
    float* out = (float*)d_out;

    const int total = in_sizes[0];                        // N*S*S*D elements
    const int n_cells = total / DDIM;                     // N*S*S (802816)
    const int N = total / (SGRID * SGRID * DDIM);         // 16384

    float* partials = (float*)d_ws;  // GRIDB floats; every block writes once

    yolo_loss_main<<<GRIDB, THREADS, 0, stream>>>(preds, targets, partials, n_cells);
    yolo_loss_reduce<<<1, RTHREADS, 0, stream>>>(partials, GRIDB, 1.0f / (float)N, out);
}